// Round 1
// 1087.398 us; speedup vs baseline: 1.0527x; 1.0527x over previous
//
#include <hip/hip_runtime.h>
#include <cmath>

// ---------------------------------------------------------------------------
// NeWCRFBlock: unary MLP + window-attention + MLP, B=8 C=256 H=W=128 WS=8 NH=8
// Round-3 changes:
//   * gemm_bt: global_load_lds width-16 staging (m97 pattern), linear LDS.
//   * attn: base-2 no-max softmax, C-layout bias prepack, sigma-permuted K so
//     P-writes vectorize (cvt_pk + ds_write_b64), O^T-swapped PV so O-stores
//     vectorize, 51200B LDS (3 blocks/CU), barrier-free, setprio on MFMA.
//   * rpb_gather: emits bias * log2e pre-packed in MFMA C-fragment layout,
//     key-token sigma-permuted.
// Workspace map unchanged (peak 194 MiB).
// ---------------------------------------------------------------------------

typedef unsigned short u16;
typedef unsigned int u32;
typedef __bf16 bf16x8 __attribute__((ext_vector_type(8)));
typedef float f32x4 __attribute__((ext_vector_type(4)));

#define EPI_NONE 0
#define EPI_GELU 1
#define EPI_WINREV 2
#define EPI_ADD 3

#define MTOK 131072
#define CC 256
#define HWC 16384

__device__ __forceinline__ float b2f(u16 u) {
    union { u32 i; float f; } x; x.i = ((u32)u) << 16; return x.f;
}
__device__ __forceinline__ u16 f2b(float f) {
    union { float f; u32 i; } x; x.f = f;
    u32 r = x.i + 0x7fffu + ((x.i >> 16) & 1u);
    return (u16)(r >> 16);
}
__device__ __forceinline__ u32 cvtpk(float lo, float hi) {
    u32 r;
    asm("v_cvt_pk_bf16_f32 %0, %1, %2" : "=v"(r) : "v"(lo), "v"(hi));
    return r;
}
__device__ __forceinline__ float gelu_f(float v) {
    return 0.5f * v * (1.0f + erff(v * 0.7071067811865475f));
}

// ---------------------------------------------------------------------------
// f32 -> bf16 elementwise convert (8 elems/thread)
// ---------------------------------------------------------------------------
__global__ __launch_bounds__(256) void cvt_f32_bf16(
    const float* __restrict__ src, u16* __restrict__ dst, long n)
{
    long i = ((long)blockIdx.x * 256 + threadIdx.x) * 8;
    if (i >= n) return;
    float4 a = *(const float4*)(src + i);
    float4 b = *(const float4*)(src + i + 4);
    union { uint4 v; u16 u[8]; } o;
    o.u[0] = f2b(a.x); o.u[1] = f2b(a.y); o.u[2] = f2b(a.z); o.u[3] = f2b(a.w);
    o.u[4] = f2b(b.x); o.u[5] = f2b(b.y); o.u[6] = f2b(b.z); o.u[7] = f2b(b.w);
    *(uint4*)(dst + i) = o.v;
}

// ---------------------------------------------------------------------------
// Weight transpose + downcast: dst_bf16[n*K+k] = src_f32[k*N+n]
// ---------------------------------------------------------------------------
__global__ __launch_bounds__(256) void transpose_f32_bf16(
    const float* __restrict__ src, u16* __restrict__ dst, int K, int N)
{
    __shared__ float t[32][33];
    const int k0 = blockIdx.x * 32, n0 = blockIdx.y * 32;
    const int tx = threadIdx.x & 31, ty = threadIdx.x >> 5;
    for (int i = ty; i < 32; i += 8)
        t[i][tx] = src[(long)(k0 + i) * N + n0 + tx];
    __syncthreads();
    for (int i = ty; i < 32; i += 8)
        dst[(long)(n0 + i) * K + k0 + tx] = f2b(t[tx][i]);
}

// ---------------------------------------------------------------------------
// Bias prepack for attn (f32):
//   biasp[h][(mi*4+ni)*256 + lane*4 + r] = log2(e) * rpb[rel[row*64+tok]*8+h]
//   row = mi*16 + (lane>>4)*4 + r   (query index, MFMA C row)
//   tok = 4*(lane&15) + ni          (key index, sigma-permuted MFMA C col)
// ---------------------------------------------------------------------------
__global__ __launch_bounds__(256) void rpb_gather(
    const float* __restrict__ rpb, const int* __restrict__ rel, float* __restrict__ outb)
{
    int e = blockIdx.x * 256 + threadIdx.x;   // 32768 total
    int h = e >> 12, idx = e & 4095;
    int mi = idx >> 10, ni = (idx >> 8) & 3, lane = (idx >> 2) & 63, r = idx & 3;
    int row = mi * 16 + (lane >> 4) * 4 + r;
    int tok = 4 * (lane & 15) + ni;
    outb[e] = 1.4426950408889634f * rpb[rel[row * 64 + tok] * 8 + h];
}

// ---------------------------------------------------------------------------
// Window partition + LayerNorm over C=256. feat f32 (B,C,H,W) -> xn bf16.
// One block per window (2048). tile layout [c][n] stride 65.
// ---------------------------------------------------------------------------
__global__ __launch_bounds__(256) void win_ln(
    const float* __restrict__ feat, const float* __restrict__ g1,
    const float* __restrict__ be1, u16* __restrict__ xn)
{
    __shared__ u16 tile[256 * 65];
    __shared__ float red1[256];
    __shared__ float red2[256];
    __shared__ float mu_s[64];
    __shared__ float rs_s[64];
    const int wid = blockIdx.x;
    const int bI = wid >> 8, rem = wid & 255, wh = rem >> 4, ww = rem & 15;
    const int c = threadIdx.x;
    const float* fp = feat + ((long)(bI * CC + c)) * HWC + (wh * 8) * 128 + ww * 8;
#pragma unroll
    for (int i = 0; i < 8; i++) {
        float4 a = *(const float4*)(fp + i * 128);
        float4 b = *(const float4*)(fp + i * 128 + 4);
        tile[c * 65 + i * 8 + 0] = f2b(a.x);
        tile[c * 65 + i * 8 + 1] = f2b(a.y);
        tile[c * 65 + i * 8 + 2] = f2b(a.z);
        tile[c * 65 + i * 8 + 3] = f2b(a.w);
        tile[c * 65 + i * 8 + 4] = f2b(b.x);
        tile[c * 65 + i * 8 + 5] = f2b(b.y);
        tile[c * 65 + i * 8 + 6] = f2b(b.z);
        tile[c * 65 + i * 8 + 7] = f2b(b.w);
    }
    __syncthreads();
    {
        const int n = threadIdx.x & 63, p = threadIdx.x >> 6;
        float s1 = 0.f, s2 = 0.f;
        for (int j = 0; j < 64; j++) {
            float v = b2f(tile[(p * 64 + j) * 65 + n]);
            s1 += v; s2 += v * v;
        }
        red1[n * 4 + p] = s1; red2[n * 4 + p] = s2;
    }
    __syncthreads();
    if (threadIdx.x < 64) {
        int t = threadIdx.x;
        float a = red1[t * 4] + red1[t * 4 + 1] + red1[t * 4 + 2] + red1[t * 4 + 3];
        float b = red2[t * 4] + red2[t * 4 + 1] + red2[t * 4 + 2] + red2[t * 4 + 3];
        float mu = a * (1.f / 256.f);
        float var = b * (1.f / 256.f) - mu * mu;
        mu_s[t] = mu;
        rs_s[t] = rsqrtf(var + 1e-5f);
    }
    __syncthreads();
    const float gc = g1[c], bc = be1[c];
    u16* xp = xn + (long)wid * 64 * 256 + c;
    for (int n2 = 0; n2 < 64; n2++) {
        float v = (b2f(tile[c * 65 + n2]) - mu_s[n2]) * rs_s[n2] * gc + bc;
        xp[n2 * 256] = f2b(v);
    }
}

// ---------------------------------------------------------------------------
// Row LayerNorm (256 cols), x2 bf16 in -> tch bf16 out; g2/be2 f32.
// One wave per row, 4 rows/block.
// ---------------------------------------------------------------------------
__global__ __launch_bounds__(256) void ln_rows(
    const u16* __restrict__ x, const float* __restrict__ g2,
    const float* __restrict__ be2, u16* __restrict__ out)
{
    const int wave = threadIdx.x >> 6, lane = threadIdx.x & 63;
    const long row = (long)blockIdx.x * 4 + wave;
    union { uint2 v; u16 u[4]; } pk;
    pk.v = *(const uint2*)(x + row * 256 + lane * 4);
    float v0 = b2f(pk.u[0]), v1 = b2f(pk.u[1]), v2 = b2f(pk.u[2]), v3 = b2f(pk.u[3]);
    float s1 = v0 + v1 + v2 + v3;
    float s2 = v0 * v0 + v1 * v1 + v2 * v2 + v3 * v3;
    for (int off = 1; off < 64; off <<= 1) {
        s1 += __shfl_xor(s1, off);
        s2 += __shfl_xor(s2, off);
    }
    float mu = s1 * (1.f / 256.f);
    float var = s2 * (1.f / 256.f) - mu * mu;
    float rs = rsqrtf(var + 1e-5f);
    float4 go = *(const float4*)(g2 + lane * 4);
    float4 bo2 = *(const float4*)(be2 + lane * 4);
    union { uint2 v; u16 u[4]; } ot;
    ot.u[0] = f2b((v0 - mu) * rs * go.x + bo2.x);
    ot.u[1] = f2b((v1 - mu) * rs * go.y + bo2.y);
    ot.u[2] = f2b((v2 - mu) * rs * go.z + bo2.z);
    ot.u[3] = f2b((v3 - mu) * rs * go.w + bo2.w);
    *(uint2*)(out + row * 256 + lane * 4) = ot.v;
}

// ---------------------------------------------------------------------------
// MFMA GEMM: out[M,N] = A[M,K](bf16) @ BT[N,K]^T(bf16) + bias(f32), EPI.
// 128x128 tile, BK=32, 4 waves x (64x64), bf16 16x16x32 MFMA.
// Staging via global_load_lds width-16 (async, linear LDS dest).
// OUTF32: write f32 (final) else bf16. res (residual) always bf16.
// ---------------------------------------------------------------------------
template <int EPI, bool OUTF32>
__global__ __launch_bounds__(256) void gemm_bt(
    const u16* __restrict__ A, const u16* __restrict__ BT,
    const float* __restrict__ bias, void* __restrict__ outv,
    const u16* __restrict__ res, int M, int N, int K)
{
    __shared__ u16 As[128 * 32];
    __shared__ u16 Bs[128 * 32];
    const int tid = threadIdx.x;
    const int m0 = blockIdx.x * 128;
    const int n0 = blockIdx.y * 128;
    const int wave = tid >> 6, lane = tid & 63;
    const int wm = wave >> 1, wn = wave & 1;
    const int quad = lane >> 4, l16 = lane & 15;

    f32x4 acc[4][4];
#pragma unroll
    for (int i = 0; i < 4; i++)
#pragma unroll
        for (int j = 0; j < 4; j++) acc[i][j] = (f32x4){0.f, 0.f, 0.f, 0.f};

    // wave stages tile rows [wave*32, wave*32+32): 2 x 1KiB per matrix.
    // LDS dest is lane-linear (base + lane*16B) as global_load_lds requires.
    const int srow = wave * 32 + (lane >> 2);
    const int scol = (lane & 3) * 8;
    const u16* gA = A + (long)(m0 + srow) * K + scol;
    const u16* gB = BT + (long)(n0 + srow) * K + scol;
    u16* lA = &As[srow * 32 + scol];
    u16* lB = &Bs[srow * 32 + scol];

    for (int k0 = 0; k0 < K; k0 += 32) {
        __syncthreads();   // all waves done reading previous tile
        __builtin_amdgcn_global_load_lds(
            (const __attribute__((address_space(1))) void*)(gA + k0),
            (__attribute__((address_space(3))) void*)lA, 16, 0, 0);
        __builtin_amdgcn_global_load_lds(
            (const __attribute__((address_space(1))) void*)(gA + k0 + 16 * K),
            (__attribute__((address_space(3))) void*)(lA + 16 * 32), 16, 0, 0);
        __builtin_amdgcn_global_load_lds(
            (const __attribute__((address_space(1))) void*)(gB + k0),
            (__attribute__((address_space(3))) void*)lB, 16, 0, 0);
        __builtin_amdgcn_global_load_lds(
            (const __attribute__((address_space(1))) void*)(gB + k0 + 16 * K),
            (__attribute__((address_space(3))) void*)(lB + 16 * 32), 16, 0, 0);
        __syncthreads();   // vmcnt(0) drained before barrier -> tile ready
        bf16x8 af[4], bfr[4];
#pragma unroll
        for (int mi = 0; mi < 4; mi++)
            af[mi] = *(const bf16x8*)&As[(wm * 64 + mi * 16 + l16) * 32 + quad * 8];
#pragma unroll
        for (int ni = 0; ni < 4; ni++)
            bfr[ni] = *(const bf16x8*)&Bs[(wn * 64 + ni * 16 + l16) * 32 + quad * 8];
#pragma unroll
        for (int mi = 0; mi < 4; mi++)
#pragma unroll
            for (int ni = 0; ni < 4; ni++)
                acc[mi][ni] = __builtin_amdgcn_mfma_f32_16x16x32_bf16(
                    af[mi], bfr[ni], acc[mi][ni], 0, 0, 0);
    }

    float bv[4];
#pragma unroll
    for (int ni = 0; ni < 4; ni++) bv[ni] = bias[n0 + wn * 64 + ni * 16 + l16];

#pragma unroll
    for (int mi = 0; mi < 4; mi++) {
#pragma unroll
        for (int r = 0; r < 4; r++) {
            int row = m0 + wm * 64 + mi * 16 + quad * 4 + r;
            long orow;
            if constexpr (EPI == EPI_WINREV) {
                int wI = row >> 6, n = row & 63;
                int bI = wI >> 8, rem = wI & 255;
                int wh = rem >> 4, wwI = rem & 15;
                orow = (long)bI * HWC + (long)((wh * 8 + (n >> 3)) * 128 + wwI * 8 + (n & 7));
            } else {
                orow = row;
            }
#pragma unroll
            for (int ni = 0; ni < 4; ni++) {
                int col = n0 + wn * 64 + ni * 16 + l16;
                float v = acc[mi][ni][r] + bv[ni];
                if constexpr (EPI == EPI_GELU) v = gelu_f(v);
                if constexpr (EPI == EPI_WINREV || EPI == EPI_ADD)
                    v += b2f(res[orow * (long)N + col]);
                if constexpr (OUTF32)
                    ((float*)outv)[orow * (long)N + col] = v;
                else
                    ((u16*)outv)[orow * (long)N + col] = f2b(v);
            }
        }
    }
}

// ---------------------------------------------------------------------------
// Window attention: one wave per (window, head). Grid 4096 x 256 thr.
// q,k,v bf16. O written IN-PLACE over qb (disjoint column ownership).
//
// K-axis token permutation sigma(n) = 4*(n&15) + (n>>4) applied to K rows in
// QK^T, so each lane's 4 P-values are consecutive tokens -> packed ds_write.
// PV computed as O^T = mfma(V^T-frag, P-frag) so stores pack 4 dims/lane.
// Slot map (both P and V^T):  slot(ks,q,e) <-> tok = (e>>2)*32 + ks*16 + q*4
//   + (e&3).  Softmax in base-2, no max-subtraction (scores bounded ~0.6).
// LDS/wave: P [2][64][32]=8192B, VT [32][72]=4608B -> 51200B/block, 3 blk/CU.
// No __syncthreads: all LDS strictly per-wave.
// ---------------------------------------------------------------------------
__global__ __launch_bounds__(256, 3) void attn_kernel(
    const u16* __restrict__ qb, const u16* __restrict__ kb,
    const u16* __restrict__ vb, const float* __restrict__ biasp,
    u16* __restrict__ ob)
{
    __shared__ u16 lds[4 * 6400];
    const int wave = threadIdx.x >> 6, lane = threadIdx.x & 63;
    const int quad = lane >> 4, l16 = lane & 15;
    const int w = blockIdx.x >> 1;
    const int h = ((blockIdx.x & 1) << 2) + wave;
    u16* Pl = lds + wave * 6400;       // [2 ks][64 m][32 slots]
    u16* VT = Pl + 4096;               // [32 dims][72], slot-permuted V^T
    const long base = (long)w * 64 * 256 + h * 32;

    // ---- load Q fragments and sigma-permuted K fragments ----
    bf16x8 aq[4], bk4[4];
#pragma unroll
    for (int mi = 0; mi < 4; mi++)
        aq[mi] = *(const bf16x8*)(qb + base + (long)(mi * 16 + l16) * 256 + quad * 8);
#pragma unroll
    for (int ni = 0; ni < 4; ni++)
        bk4[ni] = *(const bf16x8*)(kb + base + (long)(4 * l16 + ni) * 256 + quad * 8);

    // ---- stage V^T with slot permutation (lane <-> token) ----
    {
        const int t = lane;
        const int s = ((t >> 4) & 1) * 32 + ((t >> 2) & 3) * 8 + (t >> 5) * 4 + (t & 3);
        const u16* vp = vb + base + (long)t * 256;
        union { uint4 v; u16 u[8]; } p0, p1, p2, p3;
        p0.v = *(const uint4*)(vp);
        p1.v = *(const uint4*)(vp + 8);
        p2.v = *(const uint4*)(vp + 16);
        p3.v = *(const uint4*)(vp + 24);
#pragma unroll
        for (int j = 0; j < 8; j++) {
            VT[j * 72 + s]        = p0.u[j];
            VT[(8 + j) * 72 + s]  = p1.u[j];
            VT[(16 + j) * 72 + s] = p2.u[j];
            VT[(24 + j) * 72 + s] = p3.u[j];
        }
    }

    // ---- S = Q @ K^T (columns sigma-permuted) ----
    f32x4 s[4][4];
#pragma unroll
    for (int i = 0; i < 4; i++)
#pragma unroll
        for (int j = 0; j < 4; j++) s[i][j] = (f32x4){0.f, 0.f, 0.f, 0.f};
    __builtin_amdgcn_s_setprio(1);
#pragma unroll
    for (int mi = 0; mi < 4; mi++)
#pragma unroll
        for (int ni = 0; ni < 4; ni++)
            s[mi][ni] = __builtin_amdgcn_mfma_f32_16x16x32_bf16(aq[mi], bk4[ni], s[mi][ni], 0, 0, 0);
    __builtin_amdgcn_s_setprio(0);

    // ---- softmax, base-2 domain, no max subtraction ----
    const float* bp = biasp + h * 4096;
    const float SC2 = 0.17677669529663687f * 1.4426950408889634f;  // scale*log2e
    const int pq = l16 & 3, pks = (l16 >> 2) & 1, ph = l16 >> 3;
#pragma unroll
    for (int mi = 0; mi < 4; mi++) {
        f32x4 bb[4];
#pragma unroll
        for (int ni = 0; ni < 4; ni++)
            bb[ni] = *(const f32x4*)(bp + ((mi * 4 + ni) << 8) + lane * 4);
#pragma unroll
        for (int r = 0; r < 4; r++) {
            float p[4];
#pragma unroll
            for (int ni = 0; ni < 4; ni++)
                p[ni] = __builtin_amdgcn_exp2f(s[mi][ni][r] * SC2 + bb[ni][r]);
            float sum = (p[0] + p[1]) + (p[2] + p[3]);
            for (int off = 1; off < 16; off <<= 1) sum += __shfl_xor(sum, off);
            float inv = __builtin_amdgcn_rcpf(sum);
            int mrow = mi * 16 + quad * 4 + r;
            uint2 w2;
            w2.x = cvtpk(p[0] * inv, p[1] * inv);
            w2.y = cvtpk(p[2] * inv, p[3] * inv);
            *(uint2*)&Pl[pks * 2048 + mrow * 32 + pq * 8 + ph * 4] = w2;
        }
    }

    // ---- O^T = V^T @ P^T  (M=32 dims, N=64 query rows, K=64 tokens) ----
    f32x4 o4[2][4];
#pragma unroll
    for (int i = 0; i < 2; i++)
#pragma unroll
        for (int j = 0; j < 4; j++) o4[i][j] = (f32x4){0.f, 0.f, 0.f, 0.f};
#pragma unroll
    for (int ks = 0; ks < 2; ks++) {
        bf16x8 at[2], pb[4];
#pragma unroll
        for (int mi = 0; mi < 2; mi++)
            at[mi] = *(const bf16x8*)&VT[(mi * 16 + l16) * 72 + ks * 32 + quad * 8];
#pragma unroll
        for (int nt = 0; nt < 4; nt++)
            pb[nt] = *(const bf16x8*)&Pl[ks * 2048 + (nt * 16 + l16) * 32 + quad * 8];
        __builtin_amdgcn_s_setprio(1);
#pragma unroll
        for (int mi = 0; mi < 2; mi++)
#pragma unroll
            for (int nt = 0; nt < 4; nt++)
                o4[mi][nt] = __builtin_amdgcn_mfma_f32_16x16x32_bf16(at[mi], pb[nt], o4[mi][nt], 0, 0, 0);
        __builtin_amdgcn_s_setprio(0);
    }

    // ---- store O (packed 4 dims/lane, in-place over this wave's q cols) ----
#pragma unroll
    for (int nt = 0; nt < 4; nt++)
#pragma unroll
        for (int mi = 0; mi < 2; mi++) {
            uint2 w2;
            w2.x = cvtpk(o4[mi][nt][0], o4[mi][nt][1]);
            w2.y = cvtpk(o4[mi][nt][2], o4[mi][nt][3]);
            *(uint2*)(ob + base + (long)(nt * 16 + l16) * 256 + mi * 16 + quad * 4) = w2;
        }
}

// ---------------------------------------------------------------------------
extern "C" void kernel_launch(void* const* d_in, const int* in_sizes, int n_in,
                              void* d_out, int out_size, void* d_ws, size_t ws_size,
                              hipStream_t stream)
{
    (void)in_sizes; (void)n_in; (void)out_size; (void)ws_size;
    const float* x    = (const float*)d_in[0];
    const float* feat = (const float*)d_in[1];
    const float* Wq = (const float*)d_in[2];   const float* bq = (const float*)d_in[3];
    const float* Wk = (const float*)d_in[4];   const float* bk = (const float*)d_in[5];
    const float* Wv = (const float*)d_in[6];   const float* bv = (const float*)d_in[7];
    const float* Wo = (const float*)d_in[8];   const float* bo = (const float*)d_in[9];
    const float* rpb = (const float*)d_in[10];
    const float* g1 = (const float*)d_in[11];  const float* be1 = (const float*)d_in[12];
    const float* g2 = (const float*)d_in[13];  const float* be2 = (const float*)d_in[14];
    const float* Wm1 = (const float*)d_in[15]; const float* bm1 = (const float*)d_in[16];
    const float* Wm2 = (const float*)d_in[17]; const float* bm2 = (const float*)d_in[18];
    const float* Wu1 = (const float*)d_in[19]; const float* bu1 = (const float*)d_in[20];
    const float* Wu2 = (const float*)d_in[21]; const float* bu2 = (const float*)d_in[22];
    const int* rel = (const int*)d_in[23];
    float* outp = (float*)d_out;

    char* ws = (char*)d_ws;
    u16* WqT  = (u16*)(ws);
    u16* WkT  = WqT + 65536;
    u16* WvT  = WkT + 65536;
    u16* WoT  = WvT + 65536;
    u16* Wu1T = WoT + 65536;
    u16* Wu2T = Wu1T + 65536;
    u16* Wm1T = Wu2T + 65536;    // 1024 x 256
    u16* Wm2T = Wm1T + 262144;   // 256 x 1024
    float* biasf = (float*)(ws + 1835008);
    const long MB = 1024L * 1024;
    u16* S0 = (u16*)(ws + 2 * MB);      // q -> O -> tch
    u16* S1 = (u16*)(ws + 66 * MB);     // k -> xb -> un -> hch
    u16* S2 = (u16*)(ws + 130 * MB);    // v -> u1h -> x2
    u16* xn  = (u16*)d_out;  // bf16 xn in first half of f32 d_out
    u16* qb  = S0;
    u16* kb  = S1;
    u16* vb  = S2;
    u16* O   = S0;     // attn output in-place over q
    u16* xb  = S1;     // x converted to bf16 (k dead after attn)
    u16* u1h = S2;     // unary hidden (v dead after attn)
    u16* un  = S1;     // unary output (xb dead after GEMM1)
    u16* x2  = S2;     // trunk (u1h dead)
    u16* tch = S0;     // mlp ln chunk (O dead after o-proj)
    u16* hch = S1;     // mlp hidden chunk (un dead)

    const dim3 blk(256);

    // weight transposes (f32 -> bf16) + bias prepack
    transpose_f32_bf16<<<dim3(8, 8), blk, 0, stream>>>(Wq, WqT, 256, 256);
    transpose_f32_bf16<<<dim3(8, 8), blk, 0, stream>>>(Wk, WkT, 256, 256);
    transpose_f32_bf16<<<dim3(8, 8), blk, 0, stream>>>(Wv, WvT, 256, 256);
    transpose_f32_bf16<<<dim3(8, 8), blk, 0, stream>>>(Wo, WoT, 256, 256);
    transpose_f32_bf16<<<dim3(8, 8), blk, 0, stream>>>(Wu1, Wu1T, 256, 256);
    transpose_f32_bf16<<<dim3(8, 8), blk, 0, stream>>>(Wu2, Wu2T, 256, 256);
    transpose_f32_bf16<<<dim3(8, 32), blk, 0, stream>>>(Wm1, Wm1T, 256, 1024);
    transpose_f32_bf16<<<dim3(32, 8), blk, 0, stream>>>(Wm2, Wm2T, 1024, 256);
    rpb_gather<<<dim3(128), blk, 0, stream>>>(rpb, rel, biasf);

    // window partition + LN: feat -> xn (bf16, in d_out)
    win_ln<<<dim3(2048), blk, 0, stream>>>(feat, g1, be1, xn);

    // qkv projections
    gemm_bt<EPI_NONE, false><<<dim3(1024, 2), blk, 0, stream>>>(xn, WqT, bq, qb, nullptr, MTOK, 256, 256);
    gemm_bt<EPI_NONE, false><<<dim3(1024, 2), blk, 0, stream>>>(xn, WkT, bk, kb, nullptr, MTOK, 256, 256);
    gemm_bt<EPI_NONE, false><<<dim3(1024, 2), blk, 0, stream>>>(xn, WvT, bv, vb, nullptr, MTOK, 256, 256);

    // window attention (O in-place over qb); k,v dead after
    attn_kernel<<<dim3(4096), blk, 0, stream>>>(qb, kb, vb, biasf, O);

    // unary path: x(f32) -> xb(bf16); gelu(xb@Wu1+bu1) -> u1h; @Wu2+bu2 -> un
    cvt_f32_bf16<<<dim3(16384), blk, 0, stream>>>(x, xb, (long)MTOK * 256);
    gemm_bt<EPI_GELU, false><<<dim3(1024, 2), blk, 0, stream>>>(xb, Wu1T, bu1, u1h, nullptr, MTOK, 256, 256);
    gemm_bt<EPI_NONE, false><<<dim3(1024, 2), blk, 0, stream>>>(u1h, Wu2T, bu2, un, nullptr, MTOK, 256, 256);

    // o-proj + window reverse + add unary -> x2 (bf16, S2; xn consumed)
    gemm_bt<EPI_WINREV, false><<<dim3(1024, 2), blk, 0, stream>>>(O, WoT, bo, x2, un, MTOK, 256, 256);

    // MLP, 4 row chunks of 32768: out = x2 + gelu(ln(x2)@Wm1+bm1)@Wm2+bm2
    for (int ch = 0; ch < 4; ch++) {
        const u16* x2c = x2 + (long)ch * 32768 * 256;
        float* outc = outp + (long)ch * 32768 * 256;
        ln_rows<<<dim3(8192), blk, 0, stream>>>(x2c, g2, be2, tch);
        gemm_bt<EPI_GELU, false><<<dim3(256, 8), blk, 0, stream>>>(tch, Wm1T, bm1, hch, nullptr, 32768, 1024, 256);
        gemm_bt<EPI_ADD, true><<<dim3(256, 2), blk, 0, stream>>>(hch, Wm2T, bm2, outc, x2c, 32768, 256, 1024);
    }
}